// Round 16
// baseline (278.549 us; speedup 1.0000x reference)
//
#include <hip/hip_runtime.h>
#include <hip/hip_bf16.h>
#include <cstdint>
#include <cstddef>

#define NB 4
#define SS 2048
#define DMODEL 512
#define NH 8
#define DKK 64

typedef __attribute__((ext_vector_type(8))) short short8;
typedef __attribute__((ext_vector_type(4))) short s16x4;
typedef __attribute__((ext_vector_type(8))) unsigned short ushort8;
typedef __attribute__((ext_vector_type(4))) float f32x4;

static __device__ __forceinline__ unsigned short f2bf(float f){
  unsigned int u = __float_as_uint(f);
  u += 0x7fff + ((u >> 16) & 1);   // round-to-nearest-even
  return (unsigned short)(u >> 16);
}

static __device__ __forceinline__ f32x4 mfma16(short8 a, short8 b, f32x4 c){
  return __builtin_amdgcn_mfma_f32_16x16x32_bf16(a, b, c, 0, 0, 0);
}

// ---------------------------------------------------------------------------
// prep_all: W transpose | q/k bf16 convert | zero macc | vs projection
// (validated R13)
// ---------------------------------------------------------------------------
__global__ __launch_bounds__(256) void prep_all(const float* __restrict__ Wq,
    const float* __restrict__ Wk, const float* __restrict__ q,
    const float* __restrict__ k, const float* __restrict__ v,
    const float* __restrict__ Wv,
    unsigned short* __restrict__ wq_t, unsigned short* __restrict__ wk_t,
    unsigned short* __restrict__ qbf, unsigned short* __restrict__ kbf,
    unsigned short* __restrict__ vst, float* __restrict__ macc){
  __shared__ float vrow[4][512];
  __shared__ float vtile[4][64];
  int blk = blockIdx.x;
  const int t = threadIdx.x;
  if (blk < 1024){
    int i = blk*256 + t;
    int h = i >> 15, d = (i >> 6) & 511, n = i & 63;
    int o = (h*64 + n)*512 + d;
    wq_t[o] = f2bf(Wq[i]);
    wk_t[o] = f2bf(Wk[i]);
  } else if (blk < 5120){
    int b2 = blk - 1024;
    const float* src = (b2 < 2048) ? q : k;
    unsigned short* dst = (b2 < 2048) ? qbf : kbf;
    size_t off = ((size_t)(b2 & 2047)*256 + t)*8;
    f32x4 f0 = *(const f32x4*)(src + off);
    f32x4 f1 = *(const f32x4*)(src + off + 4);
    ushort8 o;
    o[0]=f2bf(f0[0]); o[1]=f2bf(f0[1]); o[2]=f2bf(f0[2]); o[3]=f2bf(f0[3]);
    o[4]=f2bf(f1[0]); o[5]=f2bf(f1[1]); o[6]=f2bf(f1[2]); o[7]=f2bf(f1[3]);
    *(ushort8*)(dst + off) = o;
  } else if (blk < 5632){
    f32x4 z = {0.f,0.f,0.f,0.f};
    *(f32x4*)(macc + ((size_t)(blk-5632+512)*256 + t)*4) = z;
  } else {
    const int M = (blk - 5632)*4;
    for (int i = t; i < 4*512; i += 256)
      vrow[i>>9][i&511] = v[(size_t)(M + (i>>9))*512 + (i&511)];
    __syncthreads();
    const int r = t>>6, dv = t&63;
    float acc = 0.f;
    #pragma unroll 8
    for (int d = 0; d < 512; d++)
      acc += vrow[r][d] * Wv[d*64 + dv];
    vtile[r][dv] = acc;
    __syncthreads();
    if (t < 64){
      s16x4 o;
      o[0] = (short)f2bf(vtile[0][t]);
      o[1] = (short)f2bf(vtile[1][t]);
      o[2] = (short)f2bf(vtile[2][t]);
      o[3] = (short)f2bf(vtile[3][t]);
      int b_ = M >> 11, s0 = M & 2047;
      *(s16x4*)(vst + ((size_t)(b_*64 + t))*2048 + s0) = o;
    }
  }
}

// ---------------------------------------------------------------------------
// Projection GEMM for Q and K in one launch (validated).
// ---------------------------------------------------------------------------
__global__ __launch_bounds__(256) void proj_both(const unsigned short* __restrict__ qbf,
    const unsigned short* __restrict__ kbf, const unsigned short* __restrict__ wq_t,
    const unsigned short* __restrict__ wk_t, unsigned short* __restrict__ qs,
    unsigned short* __restrict__ ks){
  const unsigned short* A  = blockIdx.z ? kbf : qbf;
  const unsigned short* Wt = blockIdx.z ? wk_t : wq_t;
  unsigned short* outb     = blockIdx.z ? ks : qs;
  const int m0 = blockIdx.x*64;
  const int h  = blockIdx.y;
  __shared__ alignas(16) unsigned short Alds[64][40];
  __shared__ alignas(16) unsigned short Wlds[64][40];
  const int t = threadIdx.x, w = t>>6, l = t&63;
  const int srow = t>>2, sk0 = (t&3)*8;
  f32x4 acc[4] = {{0,0,0,0},{0,0,0,0},{0,0,0,0},{0,0,0,0}};
  for (int ks_=0; ks_<512; ks_+=32){
    ushort8 av  = *(const ushort8*)(A + (size_t)(m0+srow)*512 + ks_ + sk0);
    ushort8 wv8 = *(const ushort8*)(Wt + (size_t)(h*64+srow)*512 + ks_ + sk0);
    __syncthreads();
    *(ushort8*)&Alds[srow][sk0] = av;
    *(ushort8*)&Wlds[srow][sk0] = wv8;
    __syncthreads();
    short8 a = *(const short8*)&Alds[w*16 + (l&15)][(l>>4)*8];
    #pragma unroll
    for (int nt=0; nt<4; nt++){
      short8 b = *(const short8*)&Wlds[nt*16 + (l&15)][(l>>4)*8];
      acc[nt] = mfma16(a, b, acc[nt]);
    }
  }
  #pragma unroll
  for (int nt=0; nt<4; nt++){
    #pragma unroll
    for (int r=0; r<4; r++){
      int m = m0 + w*16 + (l>>4)*4 + r;
      int b_ = m >> 11, s_ = m & 2047;
      outb[(((size_t)(h*NB + b_)*SS + s_)<<6) + nt*16 + (l&15)] = f2bf(acc[nt][r]);
    }
  }
}

// ---------------------------------------------------------------------------
// Fused attention, K-tile 64: LDS 27.6KB -> 4+ blocks/CU (was 44KB -> 3),
// removing the grid-tail penalty (1024 blocks = 4/CU).  Accumulation order
// identical to R15 (kt-64 ascending == the old sub-split order).
// Swapped QK^T, f32x4 attn stores, b64 Plds writes, scalar ri (R11-validated).
// ---------------------------------------------------------------------------
__global__ __launch_bounds__(256) void attn_fused(const unsigned short* __restrict__ qsb,
    const unsigned short* __restrict__ ksb, const unsigned short* __restrict__ vstb,
    float* __restrict__ attn, float* __restrict__ macc){
  const int q0 = blockIdx.x*64, b_ = blockIdx.y, h = blockIdx.z;
  __shared__ alignas(16) unsigned short Klds[64][72];
  __shared__ alignas(16) unsigned short Vlds[64][72];    // [dv][k_local 0..63]
  __shared__ alignas(16) unsigned short Plds[4][16][72]; // [wave][q_local][s]
  const int t = threadIdx.x, w = t>>6, l = t&63;
  const unsigned short* qsrc = qsb + (((size_t)(h*NB + b_)*SS + q0)<<6);
  const unsigned short* ksrc = ksb + (((size_t)(h*NB + b_)*SS)<<6);
  const unsigned short* vsrc = vstb + (size_t)b_*64*2048;

  const int srow = t>>2, sc0 = (t&3)*16;   // staging: 64 rows x 64 cols

  short8 a0 = *(const short8*)(qsrc + (size_t)(w*16 + (l&15))*64 + (l>>4)*8);
  short8 a1 = *(const short8*)(qsrc + (size_t)(w*16 + (l&15))*64 + 32 + (l>>4)*8);

  // ---- loop 1: row sums of exp(score*scale), swapped operands ----
  float rsum = 0.f;
  for (int kt=0; kt<32; kt++){
    const unsigned short* kro = ksrc + ((size_t)(kt*64 + srow)<<6) + sc0;
    ushort8 k0 = *(const ushort8*)(kro);
    ushort8 k1 = *(const ushort8*)(kro + 8);
    __syncthreads();
    *(ushort8*)&Klds[srow][sc0]   = k0;
    *(ushort8*)&Klds[srow][sc0+8] = k1;
    __syncthreads();
    #pragma unroll
    for (int nt=0; nt<4; nt++){
      short8 b0 = *(const short8*)&Klds[nt*16 + (l&15)][(l>>4)*8];
      short8 b1 = *(const short8*)&Klds[nt*16 + (l&15)][32 + (l>>4)*8];
      f32x4 acc = {0.f,0.f,0.f,0.f};
      acc = mfma16(b0, a0, acc);   // swapped: A=K, B=Q -> C[s][q]
      acc = mfma16(b1, a1, acc);
      #pragma unroll
      for (int r=0; r<4; r++) rsum += __expf(acc[r]*0.125f);
    }
  }
  rsum += __shfl_xor(rsum, 16);
  rsum += __shfl_xor(rsum, 32);
  const float ri = 1.0f / rsum;    // per-lane q = w*16 + (l&15)

  // ---- loop 2: f32x4 attn stores + PV accumulate ----
  f32x4 occ[4] = {{0,0,0,0},{0,0,0,0},{0,0,0,0},{0,0,0,0}};
  float* arow = attn + (size_t)(h*NB + b_)*SS*SS + (size_t)q0*SS;
  float* const myrow = arow + (size_t)(w*16 + (l&15))*SS + (l>>4)*4;
  for (int kt=0; kt<32; kt++){
    const unsigned short* kro = ksrc + ((size_t)(kt*64 + srow)<<6) + sc0;
    ushort8 k0 = *(const ushort8*)(kro);
    ushort8 k1 = *(const ushort8*)(kro + 8);
    const unsigned short* vro = vsrc + (size_t)srow*2048 + kt*64 + sc0;
    ushort8 v0 = *(const ushort8*)(vro);
    ushort8 v1 = *(const ushort8*)(vro + 8);
    __syncthreads();   // prev iteration's LDS reads complete
    *(ushort8*)&Klds[srow][sc0]   = k0;  *(ushort8*)&Klds[srow][sc0+8] = k1;
    *(ushort8*)&Vlds[srow][sc0]   = v0;  *(ushort8*)&Vlds[srow][sc0+8] = v1;
    __syncthreads();   // tiles staged
    #pragma unroll
    for (int nt=0; nt<4; nt++){
      short8 b0 = *(const short8*)&Klds[nt*16 + (l&15)][(l>>4)*8];
      short8 b1 = *(const short8*)&Klds[nt*16 + (l&15)][32 + (l>>4)*8];
      f32x4 acc = {0.f,0.f,0.f,0.f};
      acc = mfma16(b0, a0, acc);   // swapped
      acc = mfma16(b1, a1, acc);
      f32x4 pr;
      s16x4 pb;
      #pragma unroll
      for (int r=0; r<4; r++){
        float p = __expf(acc[r]*0.125f) * ri;
        pr[r] = p;
        pb[r] = (short)f2bf(p);
      }
      *(f32x4*)(myrow + kt*64 + nt*16) = pr;               // dwordx4
      *(s16x4*)&Plds[w][l&15][nt*16 + (l>>4)*4] = pb;      // b64
    }
    // Plds is wave-private: per-wave LDS drain orders writes vs reads.
    asm volatile("s_waitcnt lgkmcnt(0)" ::: "memory");
    __builtin_amdgcn_sched_barrier(0);
    #pragma unroll
    for (int kk=0; kk<2; kk++){
      short8 pa = *(const short8*)&Plds[w][l&15][kk*32 + (l>>4)*8];
      #pragma unroll
      for (int n2=0; n2<4; n2++){
        short8 vb = *(const short8*)&Vlds[n2*16 + (l&15)][kk*32 + (l>>4)*8];
        occ[n2] = mfma16(pa, vb, occ[n2]);
      }
    }
  }
  #pragma unroll
  for (int n2=0; n2<4; n2++){
    #pragma unroll
    for (int r=0; r<4; r++){
      atomicAdd(macc + ((size_t)(b_*SS + q0 + w*16 + (l>>4)*4 + r)<<6) + n2*16 + (l&15),
                occ[n2][r]*0.125f);
    }
  }
}

// ---------------------------------------------------------------------------
// final_out (R15-validated LDS-tiled version, ~8us)
// ---------------------------------------------------------------------------
__global__ __launch_bounds__(256) void final_out(const float* __restrict__ macc,
    const float* __restrict__ Wo, float* __restrict__ out){
  __shared__ alignas(16) float mlds[64][68];   // macc rows (pad 68)
  __shared__ alignas(16) float wlds[64][68];   // Wo[k][n0..n0+63]
  const int t = threadIdx.x;
  const int m0 = blockIdx.x*64, n0 = blockIdx.y*64;
  {
    int row = t>>2, c0 = (t&3)*16;
    const f32x4* msrc = (const f32x4*)(macc + (size_t)(m0+row)*64 + c0);
    *(f32x4*)&mlds[row][c0]    = msrc[0];
    *(f32x4*)&mlds[row][c0+4]  = msrc[1];
    *(f32x4*)&mlds[row][c0+8]  = msrc[2];
    *(f32x4*)&mlds[row][c0+12] = msrc[3];
    const f32x4* wsrc = (const f32x4*)(Wo + (size_t)row*512 + n0 + c0);
    *(f32x4*)&wlds[row][c0]    = wsrc[0];
    *(f32x4*)&wlds[row][c0+4]  = wsrc[1];
    *(f32x4*)&wlds[row][c0+8]  = wsrc[2];
    *(f32x4*)&wlds[row][c0+12] = wsrc[3];
  }
  __syncthreads();
  const int row = t>>2, c0 = (t&3)*16;
  f32x4 a4[4] = {{0,0,0,0},{0,0,0,0},{0,0,0,0},{0,0,0,0}};
  #pragma unroll 8
  for (int k=0; k<64; k++){
    float am = mlds[row][k];
    #pragma unroll
    for (int j=0; j<4; j++)
      a4[j] += am * *(const f32x4*)&wlds[k][c0 + j*4];
  }
  float* dst = out + (size_t)(m0+row)*512 + n0 + c0;
  #pragma unroll
  for (int j=0; j<4; j++) *(f32x4*)(dst + j*4) = a4[j];
}

// ---------------------------------------------------------------------------
// Scratch plan (unchanged from R13)
// ---------------------------------------------------------------------------
extern "C" void kernel_launch(void* const* d_in, const int* in_sizes, int n_in,
                              void* d_out, int out_size, void* d_ws, size_t ws_size,
                              hipStream_t stream){
  (void)in_sizes; (void)n_in; (void)out_size; (void)ws_size;
  const float* q  = (const float*)d_in[0];
  const float* k  = (const float*)d_in[1];
  const float* v  = (const float*)d_in[2];
  const float* Wq = (const float*)d_in[3];
  const float* Wk = (const float*)d_in[4];
  const float* Wv = (const float*)d_in[5];
  const float* Wo = (const float*)d_in[6];
  float* out  = (float*)d_out;
  float* attn = out + (size_t)NB*SS*DMODEL;   // outputs concatenated: out, attn

  unsigned short* qs_buf = (unsigned short*)d_out;
  unsigned short* ks_buf = qs_buf + (size_t)NH*NB*SS*DKK;
  unsigned short* w_tail = (unsigned short*)(attn + (size_t)NH*NB*SS*SS) - (262144 + 262144);
  unsigned short* wq_t = w_tail;
  unsigned short* wk_t = w_tail + 262144;
  unsigned short* qbf = (unsigned short*)attn;                 // 8MB
  unsigned short* kbf = qbf + (size_t)NB*SS*DMODEL;            // 8MB

  unsigned short* vst  = (unsigned short*)((char*)d_ws + 262144);   // 1,048,576 B
  float* macc          = (float*)((char*)d_ws + 1310720);           // 2,097,152 B

  prep_all<<<dim3(7680), 256, 0, stream>>>(Wq, Wk, q, k, v, Wv,
                                           wq_t, wk_t, qbf, kbf, vst, macc);
  proj_both<<<dim3(128, 8, 2), 256, 0, stream>>>(qbf, kbf, wq_t, wk_t, qs_buf, ks_buf);
  attn_fused<<<dim3(32, NB, NH), 256, 0, stream>>>(qs_buf, ks_buf, vst, attn, macc);
  final_out<<<dim3(128, 8), 256, 0, stream>>>(macc, Wo, out);
}

// Round 17
// 250.590 us; speedup vs baseline: 1.1116x; 1.1116x over previous
//
#include <hip/hip_runtime.h>
#include <hip/hip_bf16.h>
#include <cstdint>
#include <cstddef>

#define NB 4
#define SS 2048
#define DMODEL 512
#define NH 8
#define DKK 64

typedef __attribute__((ext_vector_type(8))) short short8;
typedef __attribute__((ext_vector_type(4))) short s16x4;
typedef __attribute__((ext_vector_type(8))) unsigned short ushort8;
typedef __attribute__((ext_vector_type(4))) float f32x4;

static __device__ __forceinline__ unsigned short f2bf(float f){
  unsigned int u = __float_as_uint(f);
  u += 0x7fff + ((u >> 16) & 1);   // round-to-nearest-even
  return (unsigned short)(u >> 16);
}

static __device__ __forceinline__ f32x4 mfma16(short8 a, short8 b, f32x4 c){
  return __builtin_amdgcn_mfma_f32_16x16x32_bf16(a, b, c, 0, 0, 0);
}

// ---------------------------------------------------------------------------
// prep_all: W transpose | q/k bf16 convert | zero macc | vs projection
// (validated R13)
// ---------------------------------------------------------------------------
__global__ __launch_bounds__(256) void prep_all(const float* __restrict__ Wq,
    const float* __restrict__ Wk, const float* __restrict__ q,
    const float* __restrict__ k, const float* __restrict__ v,
    const float* __restrict__ Wv,
    unsigned short* __restrict__ wq_t, unsigned short* __restrict__ wk_t,
    unsigned short* __restrict__ qbf, unsigned short* __restrict__ kbf,
    unsigned short* __restrict__ vst, float* __restrict__ macc){
  __shared__ float vrow[4][512];
  __shared__ float vtile[4][64];
  int blk = blockIdx.x;
  const int t = threadIdx.x;
  if (blk < 1024){
    int i = blk*256 + t;
    int h = i >> 15, d = (i >> 6) & 511, n = i & 63;
    int o = (h*64 + n)*512 + d;
    wq_t[o] = f2bf(Wq[i]);
    wk_t[o] = f2bf(Wk[i]);
  } else if (blk < 5120){
    int b2 = blk - 1024;
    const float* src = (b2 < 2048) ? q : k;
    unsigned short* dst = (b2 < 2048) ? qbf : kbf;
    size_t off = ((size_t)(b2 & 2047)*256 + t)*8;
    f32x4 f0 = *(const f32x4*)(src + off);
    f32x4 f1 = *(const f32x4*)(src + off + 4);
    ushort8 o;
    o[0]=f2bf(f0[0]); o[1]=f2bf(f0[1]); o[2]=f2bf(f0[2]); o[3]=f2bf(f0[3]);
    o[4]=f2bf(f1[0]); o[5]=f2bf(f1[1]); o[6]=f2bf(f1[2]); o[7]=f2bf(f1[3]);
    *(ushort8*)(dst + off) = o;
  } else if (blk < 5632){
    f32x4 z = {0.f,0.f,0.f,0.f};
    *(f32x4*)(macc + ((size_t)(blk-5632+512)*256 + t)*4) = z;
  } else {
    const int M = (blk - 5632)*4;
    for (int i = t; i < 4*512; i += 256)
      vrow[i>>9][i&511] = v[(size_t)(M + (i>>9))*512 + (i&511)];
    __syncthreads();
    const int r = t>>6, dv = t&63;
    float acc = 0.f;
    #pragma unroll 8
    for (int d = 0; d < 512; d++)
      acc += vrow[r][d] * Wv[d*64 + dv];
    vtile[r][dv] = acc;
    __syncthreads();
    if (t < 64){
      s16x4 o;
      o[0] = (short)f2bf(vtile[0][t]);
      o[1] = (short)f2bf(vtile[1][t]);
      o[2] = (short)f2bf(vtile[2][t]);
      o[3] = (short)f2bf(vtile[3][t]);
      int b_ = M >> 11, s0 = M & 2047;
      *(s16x4*)(vst + ((size_t)(b_*64 + t))*2048 + s0) = o;
    }
  }
}

// ---------------------------------------------------------------------------
// Projection GEMM for Q and K in one launch (validated).
// ---------------------------------------------------------------------------
__global__ __launch_bounds__(256) void proj_both(const unsigned short* __restrict__ qbf,
    const unsigned short* __restrict__ kbf, const unsigned short* __restrict__ wq_t,
    const unsigned short* __restrict__ wk_t, unsigned short* __restrict__ qs,
    unsigned short* __restrict__ ks){
  const unsigned short* A  = blockIdx.z ? kbf : qbf;
  const unsigned short* Wt = blockIdx.z ? wk_t : wq_t;
  unsigned short* outb     = blockIdx.z ? ks : qs;
  const int m0 = blockIdx.x*64;
  const int h  = blockIdx.y;
  __shared__ alignas(16) unsigned short Alds[64][40];
  __shared__ alignas(16) unsigned short Wlds[64][40];
  const int t = threadIdx.x, w = t>>6, l = t&63;
  const int srow = t>>2, sk0 = (t&3)*8;
  f32x4 acc[4] = {{0,0,0,0},{0,0,0,0},{0,0,0,0},{0,0,0,0}};
  for (int ks_=0; ks_<512; ks_+=32){
    ushort8 av  = *(const ushort8*)(A + (size_t)(m0+srow)*512 + ks_ + sk0);
    ushort8 wv8 = *(const ushort8*)(Wt + (size_t)(h*64+srow)*512 + ks_ + sk0);
    __syncthreads();
    *(ushort8*)&Alds[srow][sk0] = av;
    *(ushort8*)&Wlds[srow][sk0] = wv8;
    __syncthreads();
    short8 a = *(const short8*)&Alds[w*16 + (l&15)][(l>>4)*8];
    #pragma unroll
    for (int nt=0; nt<4; nt++){
      short8 b = *(const short8*)&Wlds[nt*16 + (l&15)][(l>>4)*8];
      acc[nt] = mfma16(a, b, acc[nt]);
    }
  }
  #pragma unroll
  for (int nt=0; nt<4; nt++){
    #pragma unroll
    for (int r=0; r<4; r++){
      int m = m0 + w*16 + (l>>4)*4 + r;
      int b_ = m >> 11, s_ = m & 2047;
      outb[(((size_t)(h*NB + b_)*SS + s_)<<6) + nt*16 + (l&15)] = f2bf(acc[nt][r]);
    }
  }
}

// ---------------------------------------------------------------------------
// Fused attention, K-tile 128 (R15-validated structure, 182us) +
//  (1) T14 async-STAGE: tile kt+1's global loads issued after the staging
//      barrier, consumed by next iteration's ds_write -> HBM latency hides
//      under kt's MFMA/exp/store phase.  Pure scheduling, bit-identical.
//  (2) XCD-chunked swizzle: orig id i runs on XCD i%8; nid=(i&7)*128+(i>>3)
//      gives each XCD 4 whole (b,h) K-panels -> K fetched once, not 8x.
// ---------------------------------------------------------------------------
__global__ __launch_bounds__(256) void attn_fused(const unsigned short* __restrict__ qsb,
    const unsigned short* __restrict__ ksb, const unsigned short* __restrict__ vstb,
    float* __restrict__ attn, float* __restrict__ macc){
  const int lid = blockIdx.x;
  const int nid = (lid & 7)*128 + (lid >> 3);   // bijective: 1024 = 8*128
  const int q0 = (nid & 31)*64;
  const int b_ = (nid >> 5) & 3;
  const int h  = nid >> 7;
  __shared__ alignas(16) unsigned short Klds[128][72];
  __shared__ alignas(16) unsigned short Vlds[64][136];   // [dv][k_local 0..127]
  __shared__ alignas(16) unsigned short Plds[4][16][72]; // [wave][q_local][s]
  const int t = threadIdx.x, w = t>>6, l = t&63;
  const unsigned short* qsrc = qsb + (((size_t)(h*NB + b_)*SS + q0)<<6);
  const unsigned short* ksrc = ksb + (((size_t)(h*NB + b_)*SS)<<6);
  const unsigned short* vsrc = vstb + (size_t)b_*64*2048;

  const int krow = t>>1, kc = (t&1)*32;   // K staging: 128 x 64
  const int vrow = t>>2, vc = (t&3)*32;   // V staging: 64 x 128

  short8 a0 = *(const short8*)(qsrc + (size_t)(w*16 + (l&15))*64 + (l>>4)*8);
  short8 a1 = *(const short8*)(qsrc + (size_t)(w*16 + (l&15))*64 + 32 + (l>>4)*8);

  // ---- loop 1: row sums, T14-prefetched K staging ----
  float rsum = 0.f;
  {
    const unsigned short* kro = ksrc + ((size_t)krow<<6) + kc;
    ushort8 k0 = *(const ushort8*)(kro);
    ushort8 k1 = *(const ushort8*)(kro + 8);
    ushort8 k2 = *(const ushort8*)(kro + 16);
    ushort8 k3 = *(const ushort8*)(kro + 24);
    for (int kt=0; kt<16; kt++){
      __syncthreads();   // prev iteration's LDS reads complete
      *(ushort8*)&Klds[krow][kc]    = k0;  *(ushort8*)&Klds[krow][kc+8]  = k1;
      *(ushort8*)&Klds[krow][kc+16] = k2;  *(ushort8*)&Klds[krow][kc+24] = k3;
      __syncthreads();   // tile staged
      if (kt < 15){      // issue NEXT tile now; consumed at next ds_write
        const unsigned short* kr2 = ksrc + ((size_t)((kt+1)*128 + krow)<<6) + kc;
        k0 = *(const ushort8*)(kr2);
        k1 = *(const ushort8*)(kr2 + 8);
        k2 = *(const ushort8*)(kr2 + 16);
        k3 = *(const ushort8*)(kr2 + 24);
      }
      #pragma unroll
      for (int sub=0; sub<2; sub++){
        #pragma unroll
        for (int nt=0; nt<4; nt++){
          short8 b0 = *(const short8*)&Klds[sub*64 + nt*16 + (l&15)][(l>>4)*8];
          short8 b1 = *(const short8*)&Klds[sub*64 + nt*16 + (l&15)][32 + (l>>4)*8];
          f32x4 acc = {0.f,0.f,0.f,0.f};
          acc = mfma16(b0, a0, acc);   // swapped: A=K, B=Q -> C[s][q]
          acc = mfma16(b1, a1, acc);
          #pragma unroll
          for (int r=0; r<4; r++) rsum += __expf(acc[r]*0.125f);
        }
      }
    }
  }
  rsum += __shfl_xor(rsum, 16);
  rsum += __shfl_xor(rsum, 32);
  const float ri = 1.0f / rsum;    // per-lane q = w*16 + (l&15)

  // ---- loop 2: attn stores + PV, T14-prefetched K+V staging ----
  f32x4 occ[4] = {{0,0,0,0},{0,0,0,0},{0,0,0,0},{0,0,0,0}};
  float* arow = attn + (size_t)(h*NB + b_)*SS*SS + (size_t)q0*SS;
  float* const myrow = arow + (size_t)(w*16 + (l&15))*SS + (l>>4)*4;
  {
    const unsigned short* kro = ksrc + ((size_t)krow<<6) + kc;
    ushort8 k0 = *(const ushort8*)(kro);
    ushort8 k1 = *(const ushort8*)(kro + 8);
    ushort8 k2 = *(const ushort8*)(kro + 16);
    ushort8 k3 = *(const ushort8*)(kro + 24);
    const unsigned short* vro = vsrc + (size_t)vrow*2048 + vc;
    ushort8 v0 = *(const ushort8*)(vro);
    ushort8 v1 = *(const ushort8*)(vro + 8);
    ushort8 v2 = *(const ushort8*)(vro + 16);
    ushort8 v3 = *(const ushort8*)(vro + 24);
    for (int kt=0; kt<16; kt++){
      __syncthreads();   // prev iteration's LDS reads complete
      *(ushort8*)&Klds[krow][kc]    = k0;  *(ushort8*)&Klds[krow][kc+8]  = k1;
      *(ushort8*)&Klds[krow][kc+16] = k2;  *(ushort8*)&Klds[krow][kc+24] = k3;
      *(ushort8*)&Vlds[vrow][vc]    = v0;  *(ushort8*)&Vlds[vrow][vc+8]  = v1;
      *(ushort8*)&Vlds[vrow][vc+16] = v2;  *(ushort8*)&Vlds[vrow][vc+24] = v3;
      __syncthreads();   // tiles staged
      if (kt < 15){      // issue NEXT tiles now
        const unsigned short* kr2 = ksrc + ((size_t)((kt+1)*128 + krow)<<6) + kc;
        k0 = *(const ushort8*)(kr2);
        k1 = *(const ushort8*)(kr2 + 8);
        k2 = *(const ushort8*)(kr2 + 16);
        k3 = *(const ushort8*)(kr2 + 24);
        const unsigned short* vr2 = vsrc + (size_t)vrow*2048 + (kt+1)*128 + vc;
        v0 = *(const ushort8*)(vr2);
        v1 = *(const ushort8*)(vr2 + 8);
        v2 = *(const ushort8*)(vr2 + 16);
        v3 = *(const ushort8*)(vr2 + 24);
      }
      #pragma unroll
      for (int sub=0; sub<2; sub++){
        #pragma unroll
        for (int nt=0; nt<4; nt++){
          short8 b0 = *(const short8*)&Klds[sub*64 + nt*16 + (l&15)][(l>>4)*8];
          short8 b1 = *(const short8*)&Klds[sub*64 + nt*16 + (l&15)][32 + (l>>4)*8];
          f32x4 acc = {0.f,0.f,0.f,0.f};
          acc = mfma16(b0, a0, acc);
          acc = mfma16(b1, a1, acc);
          f32x4 pr;
          s16x4 pb;
          #pragma unroll
          for (int r=0; r<4; r++){
            float p = __expf(acc[r]*0.125f) * ri;
            pr[r] = p;
            pb[r] = (short)f2bf(p);
          }
          *(f32x4*)(myrow + kt*128 + sub*64 + nt*16) = pr;
          *(s16x4*)&Plds[w][l&15][nt*16 + (l>>4)*4] = pb;
        }
        asm volatile("s_waitcnt lgkmcnt(0)" ::: "memory");
        __builtin_amdgcn_sched_barrier(0);
        #pragma unroll
        for (int kk=0; kk<2; kk++){
          short8 pa = *(const short8*)&Plds[w][l&15][kk*32 + (l>>4)*8];
          #pragma unroll
          for (int n2=0; n2<4; n2++){
            short8 vb = *(const short8*)&Vlds[n2*16 + (l&15)][sub*64 + kk*32 + (l>>4)*8];
            occ[n2] = mfma16(pa, vb, occ[n2]);
          }
        }
      }
    }
  }
  #pragma unroll
  for (int n2=0; n2<4; n2++){
    #pragma unroll
    for (int r=0; r<4; r++){
      atomicAdd(macc + ((size_t)(b_*SS + q0 + w*16 + (l>>4)*4 + r)<<6) + n2*16 + (l&15),
                occ[n2][r]*0.125f);
    }
  }
}

// ---------------------------------------------------------------------------
// final_out (R15-validated LDS-tiled version, ~8us)
// ---------------------------------------------------------------------------
__global__ __launch_bounds__(256) void final_out(const float* __restrict__ macc,
    const float* __restrict__ Wo, float* __restrict__ out){
  __shared__ alignas(16) float mlds[64][68];   // macc rows (pad 68)
  __shared__ alignas(16) float wlds[64][68];   // Wo[k][n0..n0+63]
  const int t = threadIdx.x;
  const int m0 = blockIdx.x*64, n0 = blockIdx.y*64;
  {
    int row = t>>2, c0 = (t&3)*16;
    const f32x4* msrc = (const f32x4*)(macc + (size_t)(m0+row)*64 + c0);
    *(f32x4*)&mlds[row][c0]    = msrc[0];
    *(f32x4*)&mlds[row][c0+4]  = msrc[1];
    *(f32x4*)&mlds[row][c0+8]  = msrc[2];
    *(f32x4*)&mlds[row][c0+12] = msrc[3];
    const f32x4* wsrc = (const f32x4*)(Wo + (size_t)row*512 + n0 + c0);
    *(f32x4*)&wlds[row][c0]    = wsrc[0];
    *(f32x4*)&wlds[row][c0+4]  = wsrc[1];
    *(f32x4*)&wlds[row][c0+8]  = wsrc[2];
    *(f32x4*)&wlds[row][c0+12] = wsrc[3];
  }
  __syncthreads();
  const int row = t>>2, c0 = (t&3)*16;
  f32x4 a4[4] = {{0,0,0,0},{0,0,0,0},{0,0,0,0},{0,0,0,0}};
  #pragma unroll 8
  for (int k=0; k<64; k++){
    float am = mlds[row][k];
    #pragma unroll
    for (int j=0; j<4; j++)
      a4[j] += am * *(const f32x4*)&wlds[k][c0 + j*4];
  }
  float* dst = out + (size_t)(m0+row)*512 + n0 + c0;
  #pragma unroll
  for (int j=0; j<4; j++) *(f32x4*)(dst + j*4) = a4[j];
}

// ---------------------------------------------------------------------------
// Scratch plan (unchanged from R13)
// ---------------------------------------------------------------------------
extern "C" void kernel_launch(void* const* d_in, const int* in_sizes, int n_in,
                              void* d_out, int out_size, void* d_ws, size_t ws_size,
                              hipStream_t stream){
  (void)in_sizes; (void)n_in; (void)out_size; (void)ws_size;
  const float* q  = (const float*)d_in[0];
  const float* k  = (const float*)d_in[1];
  const float* v  = (const float*)d_in[2];
  const float* Wq = (const float*)d_in[3];
  const float* Wk = (const float*)d_in[4];
  const float* Wv = (const float*)d_in[5];
  const float* Wo = (const float*)d_in[6];
  float* out  = (float*)d_out;
  float* attn = out + (size_t)NB*SS*DMODEL;   // outputs concatenated: out, attn

  unsigned short* qs_buf = (unsigned short*)d_out;
  unsigned short* ks_buf = qs_buf + (size_t)NH*NB*SS*DKK;
  unsigned short* w_tail = (unsigned short*)(attn + (size_t)NH*NB*SS*SS) - (262144 + 262144);
  unsigned short* wq_t = w_tail;
  unsigned short* wk_t = w_tail + 262144;
  unsigned short* qbf = (unsigned short*)attn;                 // 8MB
  unsigned short* kbf = qbf + (size_t)NB*SS*DMODEL;            // 8MB

  unsigned short* vst  = (unsigned short*)((char*)d_ws + 262144);   // 1,048,576 B
  float* macc          = (float*)((char*)d_ws + 1310720);           // 2,097,152 B

  prep_all<<<dim3(7680), 256, 0, stream>>>(Wq, Wk, q, k, v, Wv,
                                           wq_t, wk_t, qbf, kbf, vst, macc);
  proj_both<<<dim3(128, 8, 2), 256, 0, stream>>>(qbf, kbf, wq_t, wk_t, qs_buf, ks_buf);
  attn_fused<<<dim3(1024), 256, 0, stream>>>(qs_buf, ks_buf, vst, attn, macc);
  final_out<<<dim3(128, 8), 256, 0, stream>>>(macc, Wo, out);
}

// Round 18
// 248.555 us; speedup vs baseline: 1.1207x; 1.0082x over previous
//
#include <hip/hip_runtime.h>
#include <hip/hip_bf16.h>
#include <cstdint>
#include <cstddef>

#define NB 4
#define SS 2048
#define DMODEL 512
#define NH 8
#define DKK 64

typedef __attribute__((ext_vector_type(8))) short short8;
typedef __attribute__((ext_vector_type(4))) short s16x4;
typedef __attribute__((ext_vector_type(8))) unsigned short ushort8;
typedef __attribute__((ext_vector_type(4))) float f32x4;

static __device__ __forceinline__ unsigned short f2bf(float f){
  unsigned int u = __float_as_uint(f);
  u += 0x7fff + ((u >> 16) & 1);   // round-to-nearest-even
  return (unsigned short)(u >> 16);
}

static __device__ __forceinline__ f32x4 mfma16(short8 a, short8 b, f32x4 c){
  return __builtin_amdgcn_mfma_f32_16x16x32_bf16(a, b, c, 0, 0, 0);
}

// ---------------------------------------------------------------------------
// prep_all: W transpose | q/k bf16 convert | zero macc | vs projection
// (validated R13)
// ---------------------------------------------------------------------------
__global__ __launch_bounds__(256) void prep_all(const float* __restrict__ Wq,
    const float* __restrict__ Wk, const float* __restrict__ q,
    const float* __restrict__ k, const float* __restrict__ v,
    const float* __restrict__ Wv,
    unsigned short* __restrict__ wq_t, unsigned short* __restrict__ wk_t,
    unsigned short* __restrict__ qbf, unsigned short* __restrict__ kbf,
    unsigned short* __restrict__ vst, float* __restrict__ macc){
  __shared__ float vrow[4][512];
  __shared__ float vtile[4][64];
  int blk = blockIdx.x;
  const int t = threadIdx.x;
  if (blk < 1024){
    int i = blk*256 + t;
    int h = i >> 15, d = (i >> 6) & 511, n = i & 63;
    int o = (h*64 + n)*512 + d;
    wq_t[o] = f2bf(Wq[i]);
    wk_t[o] = f2bf(Wk[i]);
  } else if (blk < 5120){
    int b2 = blk - 1024;
    const float* src = (b2 < 2048) ? q : k;
    unsigned short* dst = (b2 < 2048) ? qbf : kbf;
    size_t off = ((size_t)(b2 & 2047)*256 + t)*8;
    f32x4 f0 = *(const f32x4*)(src + off);
    f32x4 f1 = *(const f32x4*)(src + off + 4);
    ushort8 o;
    o[0]=f2bf(f0[0]); o[1]=f2bf(f0[1]); o[2]=f2bf(f0[2]); o[3]=f2bf(f0[3]);
    o[4]=f2bf(f1[0]); o[5]=f2bf(f1[1]); o[6]=f2bf(f1[2]); o[7]=f2bf(f1[3]);
    *(ushort8*)(dst + off) = o;
  } else if (blk < 5632){
    f32x4 z = {0.f,0.f,0.f,0.f};
    *(f32x4*)(macc + ((size_t)(blk-5632+512)*256 + t)*4) = z;
  } else {
    const int M = (blk - 5632)*4;
    for (int i = t; i < 4*512; i += 256)
      vrow[i>>9][i&511] = v[(size_t)(M + (i>>9))*512 + (i&511)];
    __syncthreads();
    const int r = t>>6, dv = t&63;
    float acc = 0.f;
    #pragma unroll 8
    for (int d = 0; d < 512; d++)
      acc += vrow[r][d] * Wv[d*64 + dv];
    vtile[r][dv] = acc;
    __syncthreads();
    if (t < 64){
      s16x4 o;
      o[0] = (short)f2bf(vtile[0][t]);
      o[1] = (short)f2bf(vtile[1][t]);
      o[2] = (short)f2bf(vtile[2][t]);
      o[3] = (short)f2bf(vtile[3][t]);
      int b_ = M >> 11, s0 = M & 2047;
      *(s16x4*)(vst + ((size_t)(b_*64 + t))*2048 + s0) = o;
    }
  }
}

// ---------------------------------------------------------------------------
// Projection GEMM for Q and K in one launch (validated).
// ---------------------------------------------------------------------------
__global__ __launch_bounds__(256) void proj_both(const unsigned short* __restrict__ qbf,
    const unsigned short* __restrict__ kbf, const unsigned short* __restrict__ wq_t,
    const unsigned short* __restrict__ wk_t, unsigned short* __restrict__ qs,
    unsigned short* __restrict__ ks){
  const unsigned short* A  = blockIdx.z ? kbf : qbf;
  const unsigned short* Wt = blockIdx.z ? wk_t : wq_t;
  unsigned short* outb     = blockIdx.z ? ks : qs;
  const int m0 = blockIdx.x*64;
  const int h  = blockIdx.y;
  __shared__ alignas(16) unsigned short Alds[64][40];
  __shared__ alignas(16) unsigned short Wlds[64][40];
  const int t = threadIdx.x, w = t>>6, l = t&63;
  const int srow = t>>2, sk0 = (t&3)*8;
  f32x4 acc[4] = {{0,0,0,0},{0,0,0,0},{0,0,0,0},{0,0,0,0}};
  for (int ks_=0; ks_<512; ks_+=32){
    ushort8 av  = *(const ushort8*)(A + (size_t)(m0+srow)*512 + ks_ + sk0);
    ushort8 wv8 = *(const ushort8*)(Wt + (size_t)(h*64+srow)*512 + ks_ + sk0);
    __syncthreads();
    *(ushort8*)&Alds[srow][sk0] = av;
    *(ushort8*)&Wlds[srow][sk0] = wv8;
    __syncthreads();
    short8 a = *(const short8*)&Alds[w*16 + (l&15)][(l>>4)*8];
    #pragma unroll
    for (int nt=0; nt<4; nt++){
      short8 b = *(const short8*)&Wlds[nt*16 + (l&15)][(l>>4)*8];
      acc[nt] = mfma16(a, b, acc[nt]);
    }
  }
  #pragma unroll
  for (int nt=0; nt<4; nt++){
    #pragma unroll
    for (int r=0; r<4; r++){
      int m = m0 + w*16 + (l>>4)*4 + r;
      int b_ = m >> 11, s_ = m & 2047;
      outb[(((size_t)(h*NB + b_)*SS + s_)<<6) + nt*16 + (l&15)] = f2bf(acc[nt][r]);
    }
  }
}

// ---------------------------------------------------------------------------
// Fused attention: TWO 64-q tiles per block (128 q-rows) — halves K/V staging
// traffic, barriers, and loop-1 iterations per unit work; LDS unchanged.
// K-tile 128, T14 prefetch, XCD swizzle (512 = 8*64), swapped QK^T.
// Per-q-row math sequence identical to R17 (bit-identical output).
// ---------------------------------------------------------------------------
__global__ __launch_bounds__(256) void attn_fused(const unsigned short* __restrict__ qsb,
    const unsigned short* __restrict__ ksb, const unsigned short* __restrict__ vstb,
    float* __restrict__ attn, float* __restrict__ macc){
  const int lid = blockIdx.x;                   // 0..511
  const int nid = (lid & 7)*64 + (lid >> 3);    // bijective: 512 = 8*64
  const int q0 = (nid & 15)*128;
  const int b_ = (nid >> 4) & 3;
  const int h  = nid >> 6;
  __shared__ alignas(16) unsigned short Klds[128][72];
  __shared__ alignas(16) unsigned short Vlds[64][136];   // [dv][k_local 0..127]
  __shared__ alignas(16) unsigned short Plds[4][16][72]; // [wave][q_local][s]
  const int t = threadIdx.x, w = t>>6, l = t&63;
  const unsigned short* qsrc = qsb + (((size_t)(h*NB + b_)*SS + q0)<<6);
  const unsigned short* ksrc = ksb + (((size_t)(h*NB + b_)*SS)<<6);
  const unsigned short* vsrc = vstb + (size_t)b_*64*2048;

  const int krow = t>>1, kc = (t&1)*32;   // K staging: 128 x 64
  const int vrow = t>>2, vc = (t&3)*32;   // V staging: 64 x 128

  // Q fragments for both q-tiles (A: rows q0.., B: rows q0+64..)
  short8 aA0 = *(const short8*)(qsrc + (size_t)(w*16 + (l&15))*64 + (l>>4)*8);
  short8 aA1 = *(const short8*)(qsrc + (size_t)(w*16 + (l&15))*64 + 32 + (l>>4)*8);
  short8 aB0 = *(const short8*)(qsrc + (size_t)(64 + w*16 + (l&15))*64 + (l>>4)*8);
  short8 aB1 = *(const short8*)(qsrc + (size_t)(64 + w*16 + (l&15))*64 + 32 + (l>>4)*8);

  // ---- loop 1: row sums for both q-tiles, T14-prefetched K staging ----
  float rsumA = 0.f, rsumB = 0.f;
  {
    const unsigned short* kro = ksrc + ((size_t)krow<<6) + kc;
    ushort8 k0 = *(const ushort8*)(kro);
    ushort8 k1 = *(const ushort8*)(kro + 8);
    ushort8 k2 = *(const ushort8*)(kro + 16);
    ushort8 k3 = *(const ushort8*)(kro + 24);
    for (int kt=0; kt<16; kt++){
      __syncthreads();
      *(ushort8*)&Klds[krow][kc]    = k0;  *(ushort8*)&Klds[krow][kc+8]  = k1;
      *(ushort8*)&Klds[krow][kc+16] = k2;  *(ushort8*)&Klds[krow][kc+24] = k3;
      __syncthreads();
      if (kt < 15){
        const unsigned short* kr2 = ksrc + ((size_t)((kt+1)*128 + krow)<<6) + kc;
        k0 = *(const ushort8*)(kr2);
        k1 = *(const ushort8*)(kr2 + 8);
        k2 = *(const ushort8*)(kr2 + 16);
        k3 = *(const ushort8*)(kr2 + 24);
      }
      #pragma unroll
      for (int sub=0; sub<2; sub++){
        #pragma unroll
        for (int nt=0; nt<4; nt++){
          short8 b0 = *(const short8*)&Klds[sub*64 + nt*16 + (l&15)][(l>>4)*8];
          short8 b1 = *(const short8*)&Klds[sub*64 + nt*16 + (l&15)][32 + (l>>4)*8];
          f32x4 accA = {0.f,0.f,0.f,0.f};
          accA = mfma16(b0, aA0, accA);   // swapped: A=K, B=Q -> C[s][q]
          accA = mfma16(b1, aA1, accA);
          #pragma unroll
          for (int r=0; r<4; r++) rsumA += __expf(accA[r]*0.125f);
          f32x4 accB = {0.f,0.f,0.f,0.f};
          accB = mfma16(b0, aB0, accB);
          accB = mfma16(b1, aB1, accB);
          #pragma unroll
          for (int r=0; r<4; r++) rsumB += __expf(accB[r]*0.125f);
        }
      }
    }
  }
  rsumA += __shfl_xor(rsumA, 16);
  rsumA += __shfl_xor(rsumA, 32);
  rsumB += __shfl_xor(rsumB, 16);
  rsumB += __shfl_xor(rsumB, 32);
  const float riA = 1.0f / rsumA;
  const float riB = 1.0f / rsumB;

  // ---- loop 2: attn stores + PV for both q-tiles ----
  f32x4 occA[4] = {{0,0,0,0},{0,0,0,0},{0,0,0,0},{0,0,0,0}};
  f32x4 occB[4] = {{0,0,0,0},{0,0,0,0},{0,0,0,0},{0,0,0,0}};
  float* arow = attn + (size_t)(h*NB + b_)*SS*SS + (size_t)q0*SS;
  float* const myrowA = arow + (size_t)(w*16 + (l&15))*SS + (l>>4)*4;
  float* const myrowB = myrowA + (size_t)64*SS;
  {
    const unsigned short* kro = ksrc + ((size_t)krow<<6) + kc;
    ushort8 k0 = *(const ushort8*)(kro);
    ushort8 k1 = *(const ushort8*)(kro + 8);
    ushort8 k2 = *(const ushort8*)(kro + 16);
    ushort8 k3 = *(const ushort8*)(kro + 24);
    const unsigned short* vro = vsrc + (size_t)vrow*2048 + vc;
    ushort8 v0 = *(const ushort8*)(vro);
    ushort8 v1 = *(const ushort8*)(vro + 8);
    ushort8 v2 = *(const ushort8*)(vro + 16);
    ushort8 v3 = *(const ushort8*)(vro + 24);
    for (int kt=0; kt<16; kt++){
      __syncthreads();
      *(ushort8*)&Klds[krow][kc]    = k0;  *(ushort8*)&Klds[krow][kc+8]  = k1;
      *(ushort8*)&Klds[krow][kc+16] = k2;  *(ushort8*)&Klds[krow][kc+24] = k3;
      *(ushort8*)&Vlds[vrow][vc]    = v0;  *(ushort8*)&Vlds[vrow][vc+8]  = v1;
      *(ushort8*)&Vlds[vrow][vc+16] = v2;  *(ushort8*)&Vlds[vrow][vc+24] = v3;
      __syncthreads();
      if (kt < 15){
        const unsigned short* kr2 = ksrc + ((size_t)((kt+1)*128 + krow)<<6) + kc;
        k0 = *(const ushort8*)(kr2);
        k1 = *(const ushort8*)(kr2 + 8);
        k2 = *(const ushort8*)(kr2 + 16);
        k3 = *(const ushort8*)(kr2 + 24);
        const unsigned short* vr2 = vsrc + (size_t)vrow*2048 + (kt+1)*128 + vc;
        v0 = *(const ushort8*)(vr2);
        v1 = *(const ushort8*)(vr2 + 8);
        v2 = *(const ushort8*)(vr2 + 16);
        v3 = *(const ushort8*)(vr2 + 24);
      }
      #pragma unroll
      for (int sub=0; sub<2; sub++){
        // ---- q-tile A ----
        #pragma unroll
        for (int nt=0; nt<4; nt++){
          short8 b0 = *(const short8*)&Klds[sub*64 + nt*16 + (l&15)][(l>>4)*8];
          short8 b1 = *(const short8*)&Klds[sub*64 + nt*16 + (l&15)][32 + (l>>4)*8];
          f32x4 acc = {0.f,0.f,0.f,0.f};
          acc = mfma16(b0, aA0, acc);
          acc = mfma16(b1, aA1, acc);
          f32x4 pr;
          s16x4 pb;
          #pragma unroll
          for (int r=0; r<4; r++){
            float p = __expf(acc[r]*0.125f) * riA;
            pr[r] = p;
            pb[r] = (short)f2bf(p);
          }
          *(f32x4*)(myrowA + kt*128 + sub*64 + nt*16) = pr;
          *(s16x4*)&Plds[w][l&15][nt*16 + (l>>4)*4] = pb;
        }
        asm volatile("s_waitcnt lgkmcnt(0)" ::: "memory");
        __builtin_amdgcn_sched_barrier(0);
        #pragma unroll
        for (int kk=0; kk<2; kk++){
          short8 pa = *(const short8*)&Plds[w][l&15][kk*32 + (l>>4)*8];
          #pragma unroll
          for (int n2=0; n2<4; n2++){
            short8 vb = *(const short8*)&Vlds[n2*16 + (l&15)][sub*64 + kk*32 + (l>>4)*8];
            occA[n2] = mfma16(pa, vb, occA[n2]);
          }
        }
        // ---- q-tile B (same-wave LDS program order: A's reads precede
        //      B's Plds overwrites — pattern already validated R11-R17) ----
        #pragma unroll
        for (int nt=0; nt<4; nt++){
          short8 b0 = *(const short8*)&Klds[sub*64 + nt*16 + (l&15)][(l>>4)*8];
          short8 b1 = *(const short8*)&Klds[sub*64 + nt*16 + (l&15)][32 + (l>>4)*8];
          f32x4 acc = {0.f,0.f,0.f,0.f};
          acc = mfma16(b0, aB0, acc);
          acc = mfma16(b1, aB1, acc);
          f32x4 pr;
          s16x4 pb;
          #pragma unroll
          for (int r=0; r<4; r++){
            float p = __expf(acc[r]*0.125f) * riB;
            pr[r] = p;
            pb[r] = (short)f2bf(p);
          }
          *(f32x4*)(myrowB + kt*128 + sub*64 + nt*16) = pr;
          *(s16x4*)&Plds[w][l&15][nt*16 + (l>>4)*4] = pb;
        }
        asm volatile("s_waitcnt lgkmcnt(0)" ::: "memory");
        __builtin_amdgcn_sched_barrier(0);
        #pragma unroll
        for (int kk=0; kk<2; kk++){
          short8 pa = *(const short8*)&Plds[w][l&15][kk*32 + (l>>4)*8];
          #pragma unroll
          for (int n2=0; n2<4; n2++){
            short8 vb = *(const short8*)&Vlds[n2*16 + (l&15)][sub*64 + kk*32 + (l>>4)*8];
            occB[n2] = mfma16(pa, vb, occB[n2]);
          }
        }
      }
    }
  }
  #pragma unroll
  for (int n2=0; n2<4; n2++){
    #pragma unroll
    for (int r=0; r<4; r++){
      atomicAdd(macc + ((size_t)(b_*SS + q0 + w*16 + (l>>4)*4 + r)<<6) + n2*16 + (l&15),
                occA[n2][r]*0.125f);
      atomicAdd(macc + ((size_t)(b_*SS + q0 + 64 + w*16 + (l>>4)*4 + r)<<6) + n2*16 + (l&15),
                occB[n2][r]*0.125f);
    }
  }
}

// ---------------------------------------------------------------------------
// final_out (R15-validated LDS-tiled version, ~8us)
// ---------------------------------------------------------------------------
__global__ __launch_bounds__(256) void final_out(const float* __restrict__ macc,
    const float* __restrict__ Wo, float* __restrict__ out){
  __shared__ alignas(16) float mlds[64][68];   // macc rows (pad 68)
  __shared__ alignas(16) float wlds[64][68];   // Wo[k][n0..n0+63]
  const int t = threadIdx.x;
  const int m0 = blockIdx.x*64, n0 = blockIdx.y*64;
  {
    int row = t>>2, c0 = (t&3)*16;
    const f32x4* msrc = (const f32x4*)(macc + (size_t)(m0+row)*64 + c0);
    *(f32x4*)&mlds[row][c0]    = msrc[0];
    *(f32x4*)&mlds[row][c0+4]  = msrc[1];
    *(f32x4*)&mlds[row][c0+8]  = msrc[2];
    *(f32x4*)&mlds[row][c0+12] = msrc[3];
    const f32x4* wsrc = (const f32x4*)(Wo + (size_t)row*512 + n0 + c0);
    *(f32x4*)&wlds[row][c0]    = wsrc[0];
    *(f32x4*)&wlds[row][c0+4]  = wsrc[1];
    *(f32x4*)&wlds[row][c0+8]  = wsrc[2];
    *(f32x4*)&wlds[row][c0+12] = wsrc[3];
  }
  __syncthreads();
  const int row = t>>2, c0 = (t&3)*16;
  f32x4 a4[4] = {{0,0,0,0},{0,0,0,0},{0,0,0,0},{0,0,0,0}};
  #pragma unroll 8
  for (int k=0; k<64; k++){
    float am = mlds[row][k];
    #pragma unroll
    for (int j=0; j<4; j++)
      a4[j] += am * *(const f32x4*)&wlds[k][c0 + j*4];
  }
  float* dst = out + (size_t)(m0+row)*512 + n0 + c0;
  #pragma unroll
  for (int j=0; j<4; j++) *(f32x4*)(dst + j*4) = a4[j];
}

// ---------------------------------------------------------------------------
// Scratch plan (unchanged from R13)
// ---------------------------------------------------------------------------
extern "C" void kernel_launch(void* const* d_in, const int* in_sizes, int n_in,
                              void* d_out, int out_size, void* d_ws, size_t ws_size,
                              hipStream_t stream){
  (void)in_sizes; (void)n_in; (void)out_size; (void)ws_size;
  const float* q  = (const float*)d_in[0];
  const float* k  = (const float*)d_in[1];
  const float* v  = (const float*)d_in[2];
  const float* Wq = (const float*)d_in[3];
  const float* Wk = (const float*)d_in[4];
  const float* Wv = (const float*)d_in[5];
  const float* Wo = (const float*)d_in[6];
  float* out  = (float*)d_out;
  float* attn = out + (size_t)NB*SS*DMODEL;   // outputs concatenated: out, attn

  unsigned short* qs_buf = (unsigned short*)d_out;
  unsigned short* ks_buf = qs_buf + (size_t)NH*NB*SS*DKK;
  unsigned short* w_tail = (unsigned short*)(attn + (size_t)NH*NB*SS*SS) - (262144 + 262144);
  unsigned short* wq_t = w_tail;
  unsigned short* wk_t = w_tail + 262144;
  unsigned short* qbf = (unsigned short*)attn;                 // 8MB
  unsigned short* kbf = qbf + (size_t)NB*SS*DMODEL;            // 8MB

  unsigned short* vst  = (unsigned short*)((char*)d_ws + 262144);   // 1,048,576 B
  float* macc          = (float*)((char*)d_ws + 1310720);           // 2,097,152 B

  prep_all<<<dim3(7680), 256, 0, stream>>>(Wq, Wk, q, k, v, Wv,
                                           wq_t, wk_t, qbf, kbf, vst, macc);
  proj_both<<<dim3(128, 8, 2), 256, 0, stream>>>(qbf, kbf, wq_t, wk_t, qs_buf, ks_buf);
  attn_fused<<<dim3(512), 256, 0, stream>>>(qs_buf, ks_buf, vst, attn, macc);
  final_out<<<dim3(128, 8), 256, 0, stream>>>(macc, Wo, out);
}